// Round 15
// baseline (615.073 us; speedup 1.0000x reference)
//
#include <hip/hip_runtime.h>
#include <hip/hip_bf16.h>

typedef __attribute__((ext_vector_type(4))) float f32x4;
typedef __bf16 bf16x8 __attribute__((ext_vector_type(8)));
typedef __bf16 bf16x4 __attribute__((ext_vector_type(4)));
typedef int int4v __attribute__((ext_vector_type(4)));

#define TOKENS 16384
#define DIM    2048
#define NKVQ   3072   // Yb row stride (cols 0..1023 = K, 1024..2047 = V)

__device__ __forceinline__ void gload_lds16(const void* g, void* l) {
  __builtin_amdgcn_global_load_lds((const __attribute__((address_space(1))) void*)g,
                                   (__attribute__((address_space(3))) void*)l, 16, 0, 0);
}

// ---------------- cast fp32 -> bf16, 8 elems/thread ----------------
__global__ void cast8_kernel(const float* __restrict__ src, __bf16* __restrict__ dst, int n8) {
  int i = blockIdx.x * blockDim.x + threadIdx.x;
  if (i >= n8) return;
  const float4* s = (const float4*)src;
  float4 a = s[2 * i], b = s[2 * i + 1];
  bf16x8 o;
  o[0] = (__bf16)a.x; o[1] = (__bf16)a.y; o[2] = (__bf16)a.z; o[3] = (__bf16)a.w;
  o[4] = (__bf16)b.x; o[5] = (__bf16)b.y; o[6] = (__bf16)b.z; o[7] = (__bf16)b.w;
  ((bf16x8*)dst)[i] = o;
}

// -------- fused weight prep: Wg -> W1 interleaved gate rows; Wk,Wv -> Wkv (bf16) --------
// block-uniform branches: blocks [0,2048) Wg, [2048,3072) Wk, [3072,4096) Wv.
__global__ void prep_weights_kernel(const float* __restrict__ Wg, const float* __restrict__ Wk,
                                    const float* __restrict__ Wv, __bf16* __restrict__ W1,
                                    __bf16* __restrict__ Wkv) {
  int i = blockIdx.x * blockDim.x + threadIdx.x;
  if (i < 524288) {
    int g = i >> 8, c8 = (i & 255) * 8;
    const float4* s = (const float4*)(Wg + (size_t)g * DIM + c8);
    float4 a = s[0], b = s[1];
    bf16x8 o;
    o[0] = (__bf16)a.x; o[1] = (__bf16)a.y; o[2] = (__bf16)a.z; o[3] = (__bf16)a.w;
    o[4] = (__bf16)b.x; o[5] = (__bf16)b.y; o[6] = (__bf16)b.z; o[7] = (__bf16)b.w;
    int r = 32 * (g >> 4) + (g & 15);     // interleaved gate slot
    *(bf16x8*)(W1 + (size_t)r * DIM + c8) = o;
  } else if (i < 786432) {
    int j = i - 524288;
    const float4* s = (const float4*)Wk + 2 * j;
    float4 a = s[0], b = s[1];
    bf16x8 o;
    o[0] = (__bf16)a.x; o[1] = (__bf16)a.y; o[2] = (__bf16)a.z; o[3] = (__bf16)a.w;
    o[4] = (__bf16)b.x; o[5] = (__bf16)b.y; o[6] = (__bf16)b.z; o[7] = (__bf16)b.w;
    ((bf16x8*)Wkv)[j] = o;
  } else {
    int k = i - 786432;
    const float4* s = (const float4*)Wv + 2 * k;
    float4 a = s[0], b = s[1];
    bf16x8 o;
    o[0] = (__bf16)a.x; o[1] = (__bf16)a.y; o[2] = (__bf16)a.z; o[3] = (__bf16)a.w;
    o[4] = (__bf16)b.x; o[5] = (__bf16)b.y; o[6] = (__bf16)b.z; o[7] = (__bf16)b.w;
    ((bf16x8*)(Wkv + 2097152))[k] = o;
  }
}

// ---------------- Wq [1024 x 2048] fp32 -> WqT [2048 x 1024] bf16 ----------------
__global__ void __launch_bounds__(256)
transWq_kernel(const float* __restrict__ Wq, __bf16* __restrict__ WqT) {
  __shared__ __bf16 Ts[64][68];
  const int ti = blockIdx.x >> 5, di = blockIdx.x & 31;   // 16 x 32 tiles
  const int h0 = ti << 6, d0 = di << 6;
  const int t = threadIdx.x, r0 = t >> 4, c4 = t & 15;
  #pragma unroll
  for (int i = 0; i < 4; ++i) {
    int row = r0 + i * 16;
    float4 v = *(const float4*)(Wq + (size_t)(h0 + row) * DIM + d0 + c4 * 4);
    Ts[row][c4 * 4 + 0] = (__bf16)v.x; Ts[row][c4 * 4 + 1] = (__bf16)v.y;
    Ts[row][c4 * 4 + 2] = (__bf16)v.z; Ts[row][c4 * 4 + 3] = (__bf16)v.w;
  }
  __syncthreads();
  const int d = t >> 2, sq = t & 3;
  #pragma unroll
  for (int g = 0; g < 2; ++g) {
    bf16x8 o;
    #pragma unroll
    for (int k = 0; k < 8; ++k) o[k] = Ts[sq * 16 + g * 8 + k][d];
    *(bf16x8*)(WqT + (size_t)(d0 + d) * 1024 + h0 + sq * 16 + g * 8) = o;
  }
}

// ---------------- Weff[d, h*64+k] = sum_v Wo[d, h*64+v] * mem[h,k,v] ----------------
__global__ void weff_kernel(const float* __restrict__ Wo, const float* __restrict__ mem,
                            __bf16* __restrict__ Weff) {
  int idx = blockIdx.x * blockDim.x + threadIdx.x;  // 2048*1024
  int d = idx >> 10, hk = idx & 1023, h = hk >> 6;
  const float* wo = Wo + d * 1024 + h * 64;
  const float* mm = mem + hk * 64;
  float s = 0.f;
  #pragma unroll 8
  for (int v = 0; v < 64; ++v) s += wo[v] * mm[v];
  Weff[idx] = (__bf16)s;
}

// ================= 256x256 MFMA core, BK=32, 4-buf ring (C = A @ B^T) ========================
// EXACT round-6/14 version (5/5 replay-validated passes).
__device__ __forceinline__ void gemm256_core(
    const __bf16* __restrict__ A, int lda,
    const __bf16* __restrict__ B, int ldb,
    int m0, int n0, int nt, char* sm, f32x4 acc[8][4]) {

  const int tid = threadIdx.x, lane = tid & 63, wid = tid >> 6;
  const int wr = wid >> 2, wc = wid & 3;
  const int lrow = lane & 15, kc = lane >> 4;

  int offA[8], offB[4];
  #pragma unroll
  for (int m = 0; m < 8; ++m) {
    int u = (wr * 128 + m * 16 + lrow) * 4 + kc;
    offA[m] = (u ^ ((u >> 3) & 7)) << 4;
  }
  #pragma unroll
  for (int n = 0; n < 4; ++n) {
    int u = (wc * 64 + n * 16 + lrow) * 4 + kc;
    offB[n] = ((u ^ ((u >> 3) & 7)) << 4) + 16384;
  }

  const __bf16* pSA[2]; const __bf16* pSB[2];
  #pragma unroll
  for (int s = 0; s < 2; ++s) {
    int U = s * 512 + tid;
    int u = U ^ ((U >> 3) & 7);
    pSA[s] = A + (size_t)(m0 + (u >> 2)) * lda + (u & 3) * 8;
    pSB[s] = B + (size_t)(n0 + (u >> 2)) * ldb + (u & 3) * 8;
  }

  bf16x8 bvS0[4], bvS1[4];

#define BARX() asm volatile("s_barrier" ::: "memory")
#define VM4()  asm volatile("s_waitcnt vmcnt(4)" ::: "memory")
#define VM0()  asm volatile("s_waitcnt vmcnt(0)" ::: "memory")
#define NOVM
#define NOSTAGE
#define STAGE(bb, tt) do { \
    char* sA = sm + (bb) * 32768 + tid * 16; \
    gload_lds16(pSA[0] + (tt) * 32, sA); \
    gload_lds16(pSA[1] + (tt) * 32, sA + 8192); \
    gload_lds16(pSB[0] + (tt) * 32, sA + 16384); \
    gload_lds16(pSB[1] + (tt) * 32, sA + 24576); } while (0)

#define PH(bufC, bufN, C, N, STG, WT) do { \
    const char* bC = sm + (bufC) * 32768; \
    const char* bN = sm + (bufN) * 32768; \
    bf16x8 av[8]; \
    _Pragma("unroll") for (int m = 0; m < 8; ++m) av[m] = *(const bf16x8*)(bC + offA[m]); \
    _Pragma("unroll") for (int n = 0; n < 4; ++n) bvS##N[n] = *(const bf16x8*)(bN + offB[n]); \
    STG; \
    __builtin_amdgcn_s_setprio(1); \
    _Pragma("unroll") for (int m = 0; m < 8; ++m) \
      _Pragma("unroll") for (int n = 0; n < 4; ++n) \
        acc[m][n] = __builtin_amdgcn_mfma_f32_16x16x32_bf16(av[m], bvS##C[n], acc[m][n], 0, 0, 0); \
    __builtin_amdgcn_s_setprio(0); \
    WT; BARX(); } while (0)

#define PHF(bufC, C) do { \
    const char* bC = sm + (bufC) * 32768; \
    bf16x8 av[8]; \
    _Pragma("unroll") for (int m = 0; m < 8; ++m) av[m] = *(const bf16x8*)(bC + offA[m]); \
    __builtin_amdgcn_s_setprio(1); \
    _Pragma("unroll") for (int m = 0; m < 8; ++m) \
      _Pragma("unroll") for (int n = 0; n < 4; ++n) \
        acc[m][n] = __builtin_amdgcn_mfma_f32_16x16x32_bf16(av[m], bvS##C[n], acc[m][n], 0, 0, 0); \
    __builtin_amdgcn_s_setprio(0); } while (0)

  STAGE(0, 0); STAGE(1, 1); STAGE(2, 2);
  VM4(); BARX();
  #pragma unroll
  for (int n = 0; n < 4; ++n) bvS0[n] = *(const bf16x8*)(sm + offB[n]);

  for (int i = 0, e = (nt - 4) >> 2; i < e; ++i) {
    const int t = i << 2;
    PH(0, 1, 0, 1, STAGE(3, t + 3), VM4());
    PH(1, 2, 1, 0, STAGE(0, t + 4), VM4());
    PH(2, 3, 0, 1, STAGE(1, t + 5), VM4());
    PH(3, 0, 1, 0, STAGE(2, t + 6), VM4());
  }
  PH(0, 1, 0, 1, STAGE(3, nt - 1), VM4());
  PH(1, 2, 1, 0, NOSTAGE, VM0());
  PH(2, 3, 0, 1, NOSTAGE, NOVM);
  PHF(3, 1);
#undef PH
#undef PHF
#undef STAGE
#undef BARX
#undef VM4
#undef VM0
#undef NOVM
#undef NOSTAGE
}

// ---------------- W2 split-K: W2part[ks] = Weff[:,ks*256:+256] @ WqT[:,ks*256:+256]^T ---------
__global__ void __launch_bounds__(512, 1)
w2split_kernel(const __bf16* __restrict__ Weff, const __bf16* __restrict__ WqT,
               float* __restrict__ W2part) {
  __shared__ __attribute__((aligned(16))) char smem[131072];
  const int ks = blockIdx.x >> 6, rr = blockIdx.x & 63;
  const int bm = rr >> 3, bn = rr & 7;
  const int m0 = bm * 256, n0 = bn * 256;
  f32x4 acc[8][4] = {};
  gemm256_core(Weff + ks * 256, 1024, WqT + ks * 256, 1024, m0, n0, 8, smem, acc);

  float* P = W2part + (size_t)ks * 4194304;
  const int tid = threadIdx.x, wid = tid >> 6, lane = tid & 63;
  const int wr = wid >> 2, wc = wid & 3;
  const int crow = (lane >> 4) << 2, ccol = lane & 15;
  #pragma unroll
  for (int f = 0; f < 8; ++f) {
    int row = m0 + wr * 128 + f * 16 + crow;
    #pragma unroll
    for (int n = 0; n < 4; ++n) {
      int col = n0 + wc * 64 + n * 16 + ccol;
      #pragma unroll
      for (int j = 0; j < 4; ++j)
        P[(size_t)(row + j) * 2048 + col] = acc[f][n][j];
    }
  }
}

// ---------------- W2 reduce -> W1 interleaved readout rows (bf16) ----------------
__global__ void w2reduce_kernel(const float* __restrict__ W2part, __bf16* __restrict__ W1) {
  int i4 = blockIdx.x * blockDim.x + threadIdx.x;   // 1048576
  float4 s = ((const float4*)W2part)[i4];
  #pragma unroll
  for (int k = 1; k < 4; ++k) {
    float4 p = ((const float4*)(W2part + (size_t)k * 4194304))[i4];
    s.x += p.x; s.y += p.y; s.z += p.z; s.w += p.w;
  }
  int d = i4 >> 9, e4 = i4 & 511;
  int r = 32 * (d >> 4) + 16 + (d & 15);            // interleaved readout slot
  bf16x4 o; o[0] = (__bf16)s.x; o[1] = (__bf16)s.y; o[2] = (__bf16)s.z; o[3] = (__bf16)s.w;
  *(bf16x4*)(W1 + (size_t)r * DIM + e4 * 4) = o;
}

// -------- GEMM_main: out = hidden + sigmoid(X@Wg^T) * (X@W2^T), W1 interleaved, N=4096 --------
__global__ void __launch_bounds__(512, 1)
gemm_main_kernel(const __bf16* __restrict__ Xb, const __bf16* __restrict__ W1,
                 const float* __restrict__ hidden, float* __restrict__ out) {
  __shared__ __attribute__((aligned(16))) char smem[131072];
  const int x = blockIdx.x & 7;        // XCD
  const int l = blockIdx.x >> 3;       // 0..127
  const int bm = x * 8 + (l & 7);      // 0..63
  const int bn = l >> 3;               // 0..15
  const int m0 = bm * 256, n0 = bn * 256;
  f32x4 acc[8][4] = {};
  gemm256_core(Xb, DIM, W1, DIM, m0, n0, 64, smem, acc);

  const int tid = threadIdx.x, wid = tid >> 6, lane = tid & 63;
  const int wr = wid >> 2, wc = wid & 3;
  const int crow = (lane >> 4) << 2, ccol = lane & 15;
  #pragma unroll
  for (int f = 0; f < 8; ++f) {
    int row = m0 + wr * 128 + f * 16 + crow;
    #pragma unroll
    for (int np = 0; np < 2; ++np) {
      int col = (n0 >> 1) + wc * 32 + np * 16 + ccol;
      #pragma unroll
      for (int j = 0; j < 4; ++j) {
        size_t idx = (size_t)(row + j) * DIM + col;
        float gv = 1.0f / (1.0f + __expf(-acc[f][2 * np][j]));
        out[idx] = hidden[idx] + gv * acc[f][2 * np + 1][j];
      }
    }
  }
}

// ------------- GEMM_kv: Yb[:, 0..2047] = X @ [Wk;Wv]^T  (Yb stride NKVQ=3072) ----------------
__global__ void __launch_bounds__(512, 1)
gemm_kv_kernel(const __bf16* __restrict__ Xb, const __bf16* __restrict__ Wkv,
               __bf16* __restrict__ Yb) {
  __shared__ __attribute__((aligned(16))) char smem[131072];
  const int x = blockIdx.x & 7;        // XCD
  const int l = blockIdx.x >> 3;       // 0..63
  const int bm = x * 8 + (l & 7);      // 0..63
  const int bn = l >> 3;               // 0..7
  const int m0 = bm * 256, n0 = bn * 256;
  f32x4 acc[8][4] = {};
  gemm256_core(Xb, DIM, Wkv, DIM, m0, n0, 64, smem, acc);

  __syncthreads();
  const int tid = threadIdx.x, wid = tid >> 6, lane = tid & 63;
  const int wr = wid >> 2, wc = wid & 3;
  const int crow = (lane >> 4) << 2, ccol = lane & 15;
  #pragma unroll
  for (int f = 0; f < 8; ++f)
    #pragma unroll
    for (int n = 0; n < 4; ++n)
      #pragma unroll
      for (int j = 0; j < 4; ++j) {
        int r = wr * 128 + f * 16 + crow + j;
        int c = wc * 64 + n * 16 + ccol;
        *(__bf16*)(smem + r * 512 + ((c * 2) ^ ((r & 7) << 4))) = (__bf16)acc[f][n][j];
      }
  __syncthreads();
  const int rsub = tid >> 5, ch = tid & 31;
  #pragma unroll
  for (int p = 0; p < 16; ++p) {
    int r = p * 16 + rsub;
    bf16x8 v = *(const bf16x8*)(smem + r * 512 + ((ch * 16) ^ ((r & 7) << 4)));
    __builtin_nontemporal_store(__builtin_bit_cast(int4v, v),
        (int4v*)(Yb + (size_t)(m0 + r) * NKVQ + n0 + ch * 8));
  }
}

// ---------------- memory update partials (round-9 EXACT, NKVQ stride) ----------------
__global__ void __launch_bounds__(256)
mem_update_kernel(const __bf16* __restrict__ Y, float* __restrict__ part) {
  const int h = blockIdx.x & 15, sp = blockIdx.x >> 4;
  __shared__ __attribute__((aligned(16))) __bf16 KT[64 * 32];
  __shared__ __attribute__((aligned(16))) __bf16 VT[64 * 32];
  const int tid = threadIdx.x, wid = tid >> 6, lane = tid & 63;
  const int lrow = lane & 15, lk = (lane >> 4) * 8;
  const __bf16* Kbase = Y + (size_t)sp * 1024 * NKVQ + h * 64;
  const __bf16* Vbase = Kbase + 1024;
  f32x4 acc[4] = {};
  const int t = tid >> 3, c8 = (tid & 7) * 8;
  for (int t0 = 0; t0 < 1024; t0 += 32) {
    __syncthreads();
    bf16x8 kv = *(const bf16x8*)(Kbase + (size_t)(t0 + t) * NKVQ + c8);
    bf16x8 vv = *(const bf16x8*)(Vbase + (size_t)(t0 + t) * NKVQ + c8);
    #pragma unroll
    for (int j = 0; j < 8; ++j) {
      KT[(c8 + j) * 32 + t] = kv[j];
      VT[(c8 + j) * 32 + t] = vv[j];
    }
    __syncthreads();
    bf16x8 af = *(const bf16x8*)(KT + (wid * 16 + lrow) * 32 + lk);
    #pragma unroll
    for (int n = 0; n < 4; ++n) {
      bf16x8 bf_ = *(const bf16x8*)(VT + (n * 16 + lrow) * 32 + lk);
      acc[n] = __builtin_amdgcn_mfma_f32_16x16x32_bf16(af, bf_, acc[n], 0, 0, 0);
    }
  }
  float* pp = part + ((size_t)sp * 16 + h) * 4096;
  const int crow = wid * 16 + (lane >> 4) * 4, ccol = lane & 15;
  #pragma unroll
  for (int n = 0; n < 4; ++n)
    #pragma unroll
    for (int r = 0; r < 4; ++r)
      pp[(crow + r) * 64 + n * 16 + ccol] = acc[n][r];
}

// ---------------- memory reduce: out = 0.99*mem + sum_sp part ----------------
__global__ void mem_reduce_kernel(const float* __restrict__ part, const float* __restrict__ mem,
                                  float* __restrict__ out) {
  int i = blockIdx.x * blockDim.x + threadIdx.x;
  float s = 0.99f * mem[i];
  #pragma unroll
  for (int sp = 0; sp < 16; ++sp) s += part[sp * 65536 + i];
  out[i] = s;
}

extern "C" void kernel_launch(void* const* d_in, const int* in_sizes, int n_in,
                              void* d_out, int out_size, void* d_ws, size_t ws_size,
                              hipStream_t stream) {
  const float* hidden = (const float*)d_in[0];
  const float* memory = (const float*)d_in[1];
  const float* Wk = (const float*)d_in[2];
  const float* Wv = (const float*)d_in[3];
  const float* Wq = (const float*)d_in[4];
  const float* Wg = (const float*)d_in[5];
  const float* Wo = (const float*)d_in[6];
  float* out = (float*)d_out;
  float* mem_out = out + (size_t)TOKENS * DIM;

  char* ws = (char*)d_ws;
  __bf16* Xb   = (__bf16*)(ws);                    // 16384x2048  ( 67,108,864 B)
  __bf16* W1   = (__bf16*)(ws + 67108864);         // 4096x2048   ( 16,777,216 B) interleaved
  __bf16* Wkv  = (__bf16*)(ws + 83886080);         // 2048x2048   (  8,388,608 B)
  __bf16* Weff = (__bf16*)(ws + 92274688);         // 2048x1024   (  4,194,304 B)
  __bf16* WqT  = (__bf16*)(ws + 96468992);         // 2048x1024   (  4,194,304 B)
  __bf16* Yb   = (__bf16*)(ws + 100663296);        // 16384x3072  (100,663,296 B)
  float*  W2part = (float*)(ws + 100663296);       // 4x2048x2048 fp32 (64 MB) — aliases Yb,
                                                   //   consumed by w2reduce BEFORE gemm_kv writes Yb
  float*  part = (float*)(ws + 201326592);         // 16x16x64x64 (  4,194,304 B)
  // total 205,520,896 B

  cast8_kernel<<<16384, 256, 0, stream>>>(hidden, Xb, 4194304);
  prep_weights_kernel<<<4096, 256, 0, stream>>>(Wg, Wk, Wv, W1, Wkv);
  weff_kernel<<<8192, 256, 0, stream>>>(Wo, memory, Weff);
  transWq_kernel<<<512, 256, 0, stream>>>(Wq, WqT);

  // W2 = Weff @ Wq (split-K x4) -> interleaved readout rows of W1
  w2split_kernel<<<256, 512, 0, stream>>>(Weff, WqT, W2part);
  w2reduce_kernel<<<4096, 256, 0, stream>>>(W2part, W1);

  // main fused GEMM -> out ; KV GEMM -> Yb (overwrites W2part region, already consumed)
  gemm_main_kernel<<<1024, 512, 0, stream>>>(Xb, W1, hidden, out);
  gemm_kv_kernel<<<512, 512, 0, stream>>>(Xb, Wkv, Yb);

  // memory update
  mem_update_kernel<<<256, 256, 0, stream>>>(Yb, part);
  mem_reduce_kernel<<<256, 256, 0, stream>>>(part, memory, mem_out);
}

// Round 16
// 577.331 us; speedup vs baseline: 1.0654x; 1.0654x over previous
//
#include <hip/hip_runtime.h>
#include <hip/hip_bf16.h>

typedef __attribute__((ext_vector_type(4))) float f32x4;
typedef __bf16 bf16x8 __attribute__((ext_vector_type(8)));
typedef __bf16 bf16x4 __attribute__((ext_vector_type(4)));
typedef int int4v __attribute__((ext_vector_type(4)));

#define TOKENS 16384
#define DIM    2048
#define NKVQ   3072   // Yb row stride (cols 0..1023 = K, 1024..2047 = V)

__device__ __forceinline__ void gload_lds16(const void* g, void* l) {
  __builtin_amdgcn_global_load_lds((const __attribute__((address_space(1))) void*)g,
                                   (__attribute__((address_space(3))) void*)l, 16, 0, 0);
}

__device__ __forceinline__ bf16x8 cvt8(float4 a, float4 b) {
  bf16x8 o;
  o[0] = (__bf16)a.x; o[1] = (__bf16)a.y; o[2] = (__bf16)a.z; o[3] = (__bf16)a.w;
  o[4] = (__bf16)b.x; o[5] = (__bf16)b.y; o[6] = (__bf16)b.z; o[7] = (__bf16)b.w;
  return o;
}

// ============ fused prep: ONE launch for all casts/transposes/precomputes =====================
// block ranges (grid 29184, 256 thr):
//   [0,16384)      : hidden fp32 -> Xb bf16 (8 elems/thread)
//   [16384,20480)  : Wg -> W1 interleaved gate rows; Wk,Wv -> Wkv
//   [20480,28672)  : Weff[d, h*64+k] = sum_v Wo[d,h*64+v] * mem[h,k,v]
//   [28672,29184)  : Wq [1024x2048] -> WqT [2048x1024] (LDS transpose)
// All sections independent (disjoint outputs, input-only reads).
__global__ void __launch_bounds__(256)
prep_all_kernel(const float* __restrict__ hidden, const float* __restrict__ Wg,
                const float* __restrict__ Wk, const float* __restrict__ Wv,
                const float* __restrict__ Wo, const float* __restrict__ mem,
                const float* __restrict__ Wq,
                __bf16* __restrict__ Xb, __bf16* __restrict__ W1,
                __bf16* __restrict__ Wkv, __bf16* __restrict__ Weff,
                __bf16* __restrict__ WqT) {
  __shared__ __bf16 Ts[64][68];
  const int b = blockIdx.x, t = threadIdx.x;
  if (b < 16384) {
    int i = b * 256 + t;
    const float4* s = (const float4*)hidden;
    ((bf16x8*)Xb)[i] = cvt8(s[2 * i], s[2 * i + 1]);
  } else if (b < 20480) {
    int i = (b - 16384) * 256 + t;
    if (i < 524288) {
      int g = i >> 8, c8 = (i & 255) * 8;
      const float4* s = (const float4*)(Wg + (size_t)g * DIM + c8);
      int r = 32 * (g >> 4) + (g & 15);   // interleaved gate slot
      *(bf16x8*)(W1 + (size_t)r * DIM + c8) = cvt8(s[0], s[1]);
    } else if (i < 786432) {
      int j = i - 524288;
      const float4* s = (const float4*)Wk + 2 * j;
      ((bf16x8*)Wkv)[j] = cvt8(s[0], s[1]);
    } else {
      int k = i - 786432;
      const float4* s = (const float4*)Wv + 2 * k;
      ((bf16x8*)(Wkv + 2097152))[k] = cvt8(s[0], s[1]);
    }
  } else if (b < 28672) {
    int idx = (b - 20480) * 256 + t;      // 0..2097151
    int d = idx >> 10, hk = idx & 1023, h = hk >> 6;
    const float* wo = Wo + d * 1024 + h * 64;
    const float* mm = mem + hk * 64;
    float s = 0.f;
    #pragma unroll 8
    for (int v = 0; v < 64; ++v) s += wo[v] * mm[v];
    Weff[idx] = (__bf16)s;
  } else {
    int bb = b - 28672;                   // 0..511
    const int ti = bb >> 5, di = bb & 31; // 16 x 32 tiles
    const int h0 = ti << 6, d0 = di << 6;
    const int r0 = t >> 4, c4 = t & 15;
    #pragma unroll
    for (int i = 0; i < 4; ++i) {
      int row = r0 + i * 16;
      float4 v = *(const float4*)(Wq + (size_t)(h0 + row) * DIM + d0 + c4 * 4);
      Ts[row][c4 * 4 + 0] = (__bf16)v.x; Ts[row][c4 * 4 + 1] = (__bf16)v.y;
      Ts[row][c4 * 4 + 2] = (__bf16)v.z; Ts[row][c4 * 4 + 3] = (__bf16)v.w;
    }
    __syncthreads();
    const int d = t >> 2, sq = t & 3;
    #pragma unroll
    for (int g = 0; g < 2; ++g) {
      bf16x8 o;
      #pragma unroll
      for (int k = 0; k < 8; ++k) o[k] = Ts[sq * 16 + g * 8 + k][d];
      *(bf16x8*)(WqT + (size_t)(d0 + d) * 1024 + h0 + sq * 16 + g * 8) = o;
    }
  }
}

// ================= 256x256 MFMA core, BK=32, 4-buf ring (C = A @ B^T) ========================
// EXACT round-6/14 version (5/5 replay-validated passes).
__device__ __forceinline__ void gemm256_core(
    const __bf16* __restrict__ A, int lda,
    const __bf16* __restrict__ B, int ldb,
    int m0, int n0, int nt, char* sm, f32x4 acc[8][4]) {

  const int tid = threadIdx.x, lane = tid & 63, wid = tid >> 6;
  const int wr = wid >> 2, wc = wid & 3;
  const int lrow = lane & 15, kc = lane >> 4;

  int offA[8], offB[4];
  #pragma unroll
  for (int m = 0; m < 8; ++m) {
    int u = (wr * 128 + m * 16 + lrow) * 4 + kc;
    offA[m] = (u ^ ((u >> 3) & 7)) << 4;
  }
  #pragma unroll
  for (int n = 0; n < 4; ++n) {
    int u = (wc * 64 + n * 16 + lrow) * 4 + kc;
    offB[n] = ((u ^ ((u >> 3) & 7)) << 4) + 16384;
  }

  const __bf16* pSA[2]; const __bf16* pSB[2];
  #pragma unroll
  for (int s = 0; s < 2; ++s) {
    int U = s * 512 + tid;
    int u = U ^ ((U >> 3) & 7);
    pSA[s] = A + (size_t)(m0 + (u >> 2)) * lda + (u & 3) * 8;
    pSB[s] = B + (size_t)(n0 + (u >> 2)) * ldb + (u & 3) * 8;
  }

  bf16x8 bvS0[4], bvS1[4];

#define BARX() asm volatile("s_barrier" ::: "memory")
#define VM4()  asm volatile("s_waitcnt vmcnt(4)" ::: "memory")
#define VM0()  asm volatile("s_waitcnt vmcnt(0)" ::: "memory")
#define NOVM
#define NOSTAGE
#define STAGE(bb, tt) do { \
    char* sA = sm + (bb) * 32768 + tid * 16; \
    gload_lds16(pSA[0] + (tt) * 32, sA); \
    gload_lds16(pSA[1] + (tt) * 32, sA + 8192); \
    gload_lds16(pSB[0] + (tt) * 32, sA + 16384); \
    gload_lds16(pSB[1] + (tt) * 32, sA + 24576); } while (0)

#define PH(bufC, bufN, C, N, STG, WT) do { \
    const char* bC = sm + (bufC) * 32768; \
    const char* bN = sm + (bufN) * 32768; \
    bf16x8 av[8]; \
    _Pragma("unroll") for (int m = 0; m < 8; ++m) av[m] = *(const bf16x8*)(bC + offA[m]); \
    _Pragma("unroll") for (int n = 0; n < 4; ++n) bvS##N[n] = *(const bf16x8*)(bN + offB[n]); \
    STG; \
    __builtin_amdgcn_s_setprio(1); \
    _Pragma("unroll") for (int m = 0; m < 8; ++m) \
      _Pragma("unroll") for (int n = 0; n < 4; ++n) \
        acc[m][n] = __builtin_amdgcn_mfma_f32_16x16x32_bf16(av[m], bvS##C[n], acc[m][n], 0, 0, 0); \
    __builtin_amdgcn_s_setprio(0); \
    WT; BARX(); } while (0)

#define PHF(bufC, C) do { \
    const char* bC = sm + (bufC) * 32768; \
    bf16x8 av[8]; \
    _Pragma("unroll") for (int m = 0; m < 8; ++m) av[m] = *(const bf16x8*)(bC + offA[m]); \
    __builtin_amdgcn_s_setprio(1); \
    _Pragma("unroll") for (int m = 0; m < 8; ++m) \
      _Pragma("unroll") for (int n = 0; n < 4; ++n) \
        acc[m][n] = __builtin_amdgcn_mfma_f32_16x16x32_bf16(av[m], bvS##C[n], acc[m][n], 0, 0, 0); \
    __builtin_amdgcn_s_setprio(0); } while (0)

  STAGE(0, 0); STAGE(1, 1); STAGE(2, 2);
  VM4(); BARX();
  #pragma unroll
  for (int n = 0; n < 4; ++n) bvS0[n] = *(const bf16x8*)(sm + offB[n]);

  for (int i = 0, e = (nt - 4) >> 2; i < e; ++i) {
    const int t = i << 2;
    PH(0, 1, 0, 1, STAGE(3, t + 3), VM4());
    PH(1, 2, 1, 0, STAGE(0, t + 4), VM4());
    PH(2, 3, 0, 1, STAGE(1, t + 5), VM4());
    PH(3, 0, 1, 0, STAGE(2, t + 6), VM4());
  }
  PH(0, 1, 0, 1, STAGE(3, nt - 1), VM4());
  PH(1, 2, 1, 0, NOSTAGE, VM0());
  PH(2, 3, 0, 1, NOSTAGE, NOVM);
  PHF(3, 1);
#undef PH
#undef PHF
#undef STAGE
#undef BARX
#undef VM4
#undef VM0
#undef NOVM
#undef NOSTAGE
}

// ---------------- W2 GEMM (round-14 exact): W2 = Weff @ WqT^T -> W1 interleaved rows ----------
__global__ void __launch_bounds__(512, 1)
w2_kernel(const __bf16* __restrict__ Weff, const __bf16* __restrict__ WqT,
          __bf16* __restrict__ W1) {
  __shared__ __attribute__((aligned(16))) char smem[131072];
  const int bm = blockIdx.x >> 3, bn = blockIdx.x & 7;
  const int m0 = bm * 256, n0 = bn * 256;
  f32x4 acc[8][4] = {};
  gemm256_core(Weff, 1024, WqT, 1024, m0, n0, 32, smem, acc);

  const int tid = threadIdx.x, wid = tid >> 6, lane = tid & 63;
  const int wr = wid >> 2, wc = wid & 3;
  const int crow = (lane >> 4) << 2, ccol = lane & 15;
  #pragma unroll
  for (int f = 0; f < 8; ++f) {
    int base16 = (m0 + wr * 128) >> 4;
    #pragma unroll
    for (int n = 0; n < 4; ++n) {
      int col = n0 + wc * 64 + n * 16 + ccol;
      #pragma unroll
      for (int j = 0; j < 4; ++j) {
        int r = 32 * (base16 + f) + 16 + crow + j;   // interleaved W1 row (readout slot)
        W1[(size_t)r * DIM + col] = (__bf16)acc[f][n][j];
      }
    }
  }
}

// -------- GEMM_main: out = hidden + sigmoid(X@Wg^T) * (X@W2^T), W1 interleaved, N=4096 --------
__global__ void __launch_bounds__(512, 1)
gemm_main_kernel(const __bf16* __restrict__ Xb, const __bf16* __restrict__ W1,
                 const float* __restrict__ hidden, float* __restrict__ out) {
  __shared__ __attribute__((aligned(16))) char smem[131072];
  const int x = blockIdx.x & 7;        // XCD
  const int l = blockIdx.x >> 3;       // 0..127
  const int bm = x * 8 + (l & 7);      // 0..63
  const int bn = l >> 3;               // 0..15
  const int m0 = bm * 256, n0 = bn * 256;
  f32x4 acc[8][4] = {};
  gemm256_core(Xb, DIM, W1, DIM, m0, n0, 64, smem, acc);

  const int tid = threadIdx.x, wid = tid >> 6, lane = tid & 63;
  const int wr = wid >> 2, wc = wid & 3;
  const int crow = (lane >> 4) << 2, ccol = lane & 15;
  #pragma unroll
  for (int f = 0; f < 8; ++f) {
    int row = m0 + wr * 128 + f * 16 + crow;
    #pragma unroll
    for (int np = 0; np < 2; ++np) {
      int col = (n0 >> 1) + wc * 32 + np * 16 + ccol;
      #pragma unroll
      for (int j = 0; j < 4; ++j) {
        size_t idx = (size_t)(row + j) * DIM + col;
        float gv = 1.0f / (1.0f + __expf(-acc[f][2 * np][j]));
        out[idx] = hidden[idx] + gv * acc[f][2 * np + 1][j];
      }
    }
  }
}

// ------------- GEMM_kv: Yb[:, 0..2047] = X @ [Wk;Wv]^T  (Yb stride NKVQ=3072) ----------------
__global__ void __launch_bounds__(512, 1)
gemm_kv_kernel(const __bf16* __restrict__ Xb, const __bf16* __restrict__ Wkv,
               __bf16* __restrict__ Yb) {
  __shared__ __attribute__((aligned(16))) char smem[131072];
  const int x = blockIdx.x & 7;        // XCD
  const int l = blockIdx.x >> 3;       // 0..63
  const int bm = x * 8 + (l & 7);      // 0..63
  const int bn = l >> 3;               // 0..7
  const int m0 = bm * 256, n0 = bn * 256;
  f32x4 acc[8][4] = {};
  gemm256_core(Xb, DIM, Wkv, DIM, m0, n0, 64, smem, acc);

  __syncthreads();
  const int tid = threadIdx.x, wid = tid >> 6, lane = tid & 63;
  const int wr = wid >> 2, wc = wid & 3;
  const int crow = (lane >> 4) << 2, ccol = lane & 15;
  #pragma unroll
  for (int f = 0; f < 8; ++f)
    #pragma unroll
    for (int n = 0; n < 4; ++n)
      #pragma unroll
      for (int j = 0; j < 4; ++j) {
        int r = wr * 128 + f * 16 + crow + j;
        int c = wc * 64 + n * 16 + ccol;
        *(__bf16*)(smem + r * 512 + ((c * 2) ^ ((r & 7) << 4))) = (__bf16)acc[f][n][j];
      }
  __syncthreads();
  const int rsub = tid >> 5, ch = tid & 31;
  #pragma unroll
  for (int p = 0; p < 16; ++p) {
    int r = p * 16 + rsub;
    bf16x8 v = *(const bf16x8*)(smem + r * 512 + ((ch * 16) ^ ((r & 7) << 4)));
    __builtin_nontemporal_store(__builtin_bit_cast(int4v, v),
        (int4v*)(Yb + (size_t)(m0 + r) * NKVQ + n0 + ch * 8));
  }
}

// ---------------- memory update partials (round-9 EXACT, NKVQ stride) ----------------
__global__ void __launch_bounds__(256)
mem_update_kernel(const __bf16* __restrict__ Y, float* __restrict__ part) {
  const int h = blockIdx.x & 15, sp = blockIdx.x >> 4;
  __shared__ __attribute__((aligned(16))) __bf16 KT[64 * 32];
  __shared__ __attribute__((aligned(16))) __bf16 VT[64 * 32];
  const int tid = threadIdx.x, wid = tid >> 6, lane = tid & 63;
  const int lrow = lane & 15, lk = (lane >> 4) * 8;
  const __bf16* Kbase = Y + (size_t)sp * 1024 * NKVQ + h * 64;
  const __bf16* Vbase = Kbase + 1024;
  f32x4 acc[4] = {};
  const int t = tid >> 3, c8 = (tid & 7) * 8;
  for (int t0 = 0; t0 < 1024; t0 += 32) {
    __syncthreads();
    bf16x8 kv = *(const bf16x8*)(Kbase + (size_t)(t0 + t) * NKVQ + c8);
    bf16x8 vv = *(const bf16x8*)(Vbase + (size_t)(t0 + t) * NKVQ + c8);
    #pragma unroll
    for (int j = 0; j < 8; ++j) {
      KT[(c8 + j) * 32 + t] = kv[j];
      VT[(c8 + j) * 32 + t] = vv[j];
    }
    __syncthreads();
    bf16x8 af = *(const bf16x8*)(KT + (wid * 16 + lrow) * 32 + lk);
    #pragma unroll
    for (int n = 0; n < 4; ++n) {
      bf16x8 bf_ = *(const bf16x8*)(VT + (n * 16 + lrow) * 32 + lk);
      acc[n] = __builtin_amdgcn_mfma_f32_16x16x32_bf16(af, bf_, acc[n], 0, 0, 0);
    }
  }
  float* pp = part + ((size_t)sp * 16 + h) * 4096;
  const int crow = wid * 16 + (lane >> 4) * 4, ccol = lane & 15;
  #pragma unroll
  for (int n = 0; n < 4; ++n)
    #pragma unroll
    for (int r = 0; r < 4; ++r)
      pp[(crow + r) * 64 + n * 16 + ccol] = acc[n][r];
}

// ---------------- memory reduce: out = 0.99*mem + sum_sp part ----------------
__global__ void mem_reduce_kernel(const float* __restrict__ part, const float* __restrict__ mem,
                                  float* __restrict__ out) {
  int i = blockIdx.x * blockDim.x + threadIdx.x;
  float s = 0.99f * mem[i];
  #pragma unroll
  for (int sp = 0; sp < 16; ++sp) s += part[sp * 65536 + i];
  out[i] = s;
}

extern "C" void kernel_launch(void* const* d_in, const int* in_sizes, int n_in,
                              void* d_out, int out_size, void* d_ws, size_t ws_size,
                              hipStream_t stream) {
  const float* hidden = (const float*)d_in[0];
  const float* memory = (const float*)d_in[1];
  const float* Wk = (const float*)d_in[2];
  const float* Wv = (const float*)d_in[3];
  const float* Wq = (const float*)d_in[4];
  const float* Wg = (const float*)d_in[5];
  const float* Wo = (const float*)d_in[6];
  float* out = (float*)d_out;
  float* mem_out = out + (size_t)TOKENS * DIM;

  char* ws = (char*)d_ws;
  __bf16* Xb   = (__bf16*)(ws);                    // 16384x2048  ( 67,108,864 B)
  __bf16* W1   = (__bf16*)(ws + 67108864);         // 4096x2048   ( 16,777,216 B) interleaved
  __bf16* Wkv  = (__bf16*)(ws + 83886080);         // 2048x2048   (  8,388,608 B)
  __bf16* Weff = (__bf16*)(ws + 92274688);         // 2048x1024   (  4,194,304 B)
  __bf16* WqT  = (__bf16*)(ws + 96468992);         // 2048x1024   (  4,194,304 B)
  __bf16* Yb   = (__bf16*)(ws + 100663296);        // 16384x3072  (100,663,296 B)
  float*  part = (float*)(ws + 201326592);         // 16x16x64x64 (  4,194,304 B)
  // total 205,520,896 B

  // ONE prep launch: Xb, W1 gate rows, Wkv, Weff, WqT
  prep_all_kernel<<<29184, 256, 0, stream>>>(hidden, Wg, Wk, Wv, Wo, memory, Wq,
                                             Xb, W1, Wkv, Weff, WqT);

  // W2 = Weff @ Wq -> interleaved readout rows of W1 (round-14 exact)
  w2_kernel<<<64, 512, 0, stream>>>(Weff, WqT, W1);

  // main fused GEMM -> out ; KV GEMM -> Yb
  gemm_main_kernel<<<1024, 512, 0, stream>>>(Xb, W1, hidden, out);
  gemm_kv_kernel<<<512, 512, 0, stream>>>(Xb, Wkv, Yb);

  // memory update
  mem_update_kernel<<<256, 256, 0, stream>>>(Yb, part);
  mem_reduce_kernel<<<256, 256, 0, stream>>>(part, memory, mem_out);
}

// Round 17
// 574.347 us; speedup vs baseline: 1.0709x; 1.0052x over previous
//
#include <hip/hip_runtime.h>
#include <hip/hip_bf16.h>

typedef __attribute__((ext_vector_type(4))) float f32x4;
typedef __bf16 bf16x8 __attribute__((ext_vector_type(8)));
typedef __bf16 bf16x4 __attribute__((ext_vector_type(4)));
typedef int int4v __attribute__((ext_vector_type(4)));

#define TOKENS 16384
#define DIM    2048
#define NKVQ   3072   // Yb row stride (cols 0..1023 = K, 1024..2047 = V)

__device__ __forceinline__ void gload_lds16(const void* g, void* l) {
  __builtin_amdgcn_global_load_lds((const __attribute__((address_space(1))) void*)g,
                                   (__attribute__((address_space(3))) void*)l, 16, 0, 0);
}

__device__ __forceinline__ bf16x8 cvt8(float4 a, float4 b) {
  bf16x8 o;
  o[0] = (__bf16)a.x; o[1] = (__bf16)a.y; o[2] = (__bf16)a.z; o[3] = (__bf16)a.w;
  o[4] = (__bf16)b.x; o[5] = (__bf16)b.y; o[6] = (__bf16)b.z; o[7] = (__bf16)b.w;
  return o;
}

// ============ fused prep: ONE launch for all casts/transposes/precomputes =====================
// (round-16 exact; passed)
__global__ void __launch_bounds__(256)
prep_all_kernel(const float* __restrict__ hidden, const float* __restrict__ Wg,
                const float* __restrict__ Wk, const float* __restrict__ Wv,
                const float* __restrict__ Wo, const float* __restrict__ mem,
                const float* __restrict__ Wq,
                __bf16* __restrict__ Xb, __bf16* __restrict__ W1,
                __bf16* __restrict__ Wkv, __bf16* __restrict__ Weff,
                __bf16* __restrict__ WqT) {
  __shared__ __bf16 Ts[64][68];
  const int b = blockIdx.x, t = threadIdx.x;
  if (b < 16384) {
    int i = b * 256 + t;
    const float4* s = (const float4*)hidden;
    ((bf16x8*)Xb)[i] = cvt8(s[2 * i], s[2 * i + 1]);
  } else if (b < 20480) {
    int i = (b - 16384) * 256 + t;
    if (i < 524288) {
      int g = i >> 8, c8 = (i & 255) * 8;
      const float4* s = (const float4*)(Wg + (size_t)g * DIM + c8);
      int r = 32 * (g >> 4) + (g & 15);   // interleaved gate slot
      *(bf16x8*)(W1 + (size_t)r * DIM + c8) = cvt8(s[0], s[1]);
    } else if (i < 786432) {
      int j = i - 524288;
      const float4* s = (const float4*)Wk + 2 * j;
      ((bf16x8*)Wkv)[j] = cvt8(s[0], s[1]);
    } else {
      int k = i - 786432;
      const float4* s = (const float4*)Wv + 2 * k;
      ((bf16x8*)(Wkv + 2097152))[k] = cvt8(s[0], s[1]);
    }
  } else if (b < 28672) {
    int idx = (b - 20480) * 256 + t;      // 0..2097151
    int d = idx >> 10, hk = idx & 1023, h = hk >> 6;
    const float* wo = Wo + d * 1024 + h * 64;
    const float* mm = mem + hk * 64;
    float s = 0.f;
    #pragma unroll 8
    for (int v = 0; v < 64; ++v) s += wo[v] * mm[v];
    Weff[idx] = (__bf16)s;
  } else {
    int bb = b - 28672;                   // 0..511
    const int ti = bb >> 5, di = bb & 31; // 16 x 32 tiles
    const int h0 = ti << 6, d0 = di << 6;
    const int r0 = t >> 4, c4 = t & 15;
    #pragma unroll
    for (int i = 0; i < 4; ++i) {
      int row = r0 + i * 16;
      float4 v = *(const float4*)(Wq + (size_t)(h0 + row) * DIM + d0 + c4 * 4);
      Ts[row][c4 * 4 + 0] = (__bf16)v.x; Ts[row][c4 * 4 + 1] = (__bf16)v.y;
      Ts[row][c4 * 4 + 2] = (__bf16)v.z; Ts[row][c4 * 4 + 3] = (__bf16)v.w;
    }
    __syncthreads();
    const int d = t >> 2, sq = t & 3;
    #pragma unroll
    for (int g = 0; g < 2; ++g) {
      bf16x8 o;
      #pragma unroll
      for (int k = 0; k < 8; ++k) o[k] = Ts[sq * 16 + g * 8 + k][d];
      *(bf16x8*)(WqT + (size_t)(d0 + d) * 1024 + h0 + sq * 16 + g * 8) = o;
    }
  }
}

// ================= 256x256 MFMA core, BK=32, 4-buf ring (C = A @ B^T) ========================
// EXACT round-6/14/16 version (6/6 replay-validated passes).
__device__ __forceinline__ void gemm256_core(
    const __bf16* __restrict__ A, int lda,
    const __bf16* __restrict__ B, int ldb,
    int m0, int n0, int nt, char* sm, f32x4 acc[8][4]) {

  const int tid = threadIdx.x, lane = tid & 63, wid = tid >> 6;
  const int wr = wid >> 2, wc = wid & 3;
  const int lrow = lane & 15, kc = lane >> 4;

  int offA[8], offB[4];
  #pragma unroll
  for (int m = 0; m < 8; ++m) {
    int u = (wr * 128 + m * 16 + lrow) * 4 + kc;
    offA[m] = (u ^ ((u >> 3) & 7)) << 4;
  }
  #pragma unroll
  for (int n = 0; n < 4; ++n) {
    int u = (wc * 64 + n * 16 + lrow) * 4 + kc;
    offB[n] = ((u ^ ((u >> 3) & 7)) << 4) + 16384;
  }

  const __bf16* pSA[2]; const __bf16* pSB[2];
  #pragma unroll
  for (int s = 0; s < 2; ++s) {
    int U = s * 512 + tid;
    int u = U ^ ((U >> 3) & 7);
    pSA[s] = A + (size_t)(m0 + (u >> 2)) * lda + (u & 3) * 8;
    pSB[s] = B + (size_t)(n0 + (u >> 2)) * ldb + (u & 3) * 8;
  }

  bf16x8 bvS0[4], bvS1[4];

#define BARX() asm volatile("s_barrier" ::: "memory")
#define VM4()  asm volatile("s_waitcnt vmcnt(4)" ::: "memory")
#define VM0()  asm volatile("s_waitcnt vmcnt(0)" ::: "memory")
#define NOVM
#define NOSTAGE
#define STAGE(bb, tt) do { \
    char* sA = sm + (bb) * 32768 + tid * 16; \
    gload_lds16(pSA[0] + (tt) * 32, sA); \
    gload_lds16(pSA[1] + (tt) * 32, sA + 8192); \
    gload_lds16(pSB[0] + (tt) * 32, sA + 16384); \
    gload_lds16(pSB[1] + (tt) * 32, sA + 24576); } while (0)

#define PH(bufC, bufN, C, N, STG, WT) do { \
    const char* bC = sm + (bufC) * 32768; \
    const char* bN = sm + (bufN) * 32768; \
    bf16x8 av[8]; \
    _Pragma("unroll") for (int m = 0; m < 8; ++m) av[m] = *(const bf16x8*)(bC + offA[m]); \
    _Pragma("unroll") for (int n = 0; n < 4; ++n) bvS##N[n] = *(const bf16x8*)(bN + offB[n]); \
    STG; \
    __builtin_amdgcn_s_setprio(1); \
    _Pragma("unroll") for (int m = 0; m < 8; ++m) \
      _Pragma("unroll") for (int n = 0; n < 4; ++n) \
        acc[m][n] = __builtin_amdgcn_mfma_f32_16x16x32_bf16(av[m], bvS##C[n], acc[m][n], 0, 0, 0); \
    __builtin_amdgcn_s_setprio(0); \
    WT; BARX(); } while (0)

#define PHF(bufC, C) do { \
    const char* bC = sm + (bufC) * 32768; \
    bf16x8 av[8]; \
    _Pragma("unroll") for (int m = 0; m < 8; ++m) av[m] = *(const bf16x8*)(bC + offA[m]); \
    __builtin_amdgcn_s_setprio(1); \
    _Pragma("unroll") for (int m = 0; m < 8; ++m) \
      _Pragma("unroll") for (int n = 0; n < 4; ++n) \
        acc[m][n] = __builtin_amdgcn_mfma_f32_16x16x32_bf16(av[m], bvS##C[n], acc[m][n], 0, 0, 0); \
    __builtin_amdgcn_s_setprio(0); } while (0)

  STAGE(0, 0); STAGE(1, 1); STAGE(2, 2);
  VM4(); BARX();
  #pragma unroll
  for (int n = 0; n < 4; ++n) bvS0[n] = *(const bf16x8*)(sm + offB[n]);

  for (int i = 0, e = (nt - 4) >> 2; i < e; ++i) {
    const int t = i << 2;
    PH(0, 1, 0, 1, STAGE(3, t + 3), VM4());
    PH(1, 2, 1, 0, STAGE(0, t + 4), VM4());
    PH(2, 3, 0, 1, STAGE(1, t + 5), VM4());
    PH(3, 0, 1, 0, STAGE(2, t + 6), VM4());
  }
  PH(0, 1, 0, 1, STAGE(3, nt - 1), VM4());
  PH(1, 2, 1, 0, NOSTAGE, VM0());
  PH(2, 3, 0, 1, NOSTAGE, NOVM);
  PHF(3, 1);
#undef PH
#undef PHF
#undef STAGE
#undef BARX
#undef VM4
#undef VM0
#undef NOVM
#undef NOSTAGE
}

// ---------------- W2 GEMM (round-14/16 exact): W2 = Weff @ WqT^T -> W1 interleaved rows -------
__global__ void __launch_bounds__(512, 1)
w2_kernel(const __bf16* __restrict__ Weff, const __bf16* __restrict__ WqT,
          __bf16* __restrict__ W1) {
  __shared__ __attribute__((aligned(16))) char smem[131072];
  const int bm = blockIdx.x >> 3, bn = blockIdx.x & 7;
  const int m0 = bm * 256, n0 = bn * 256;
  f32x4 acc[8][4] = {};
  gemm256_core(Weff, 1024, WqT, 1024, m0, n0, 32, smem, acc);

  const int tid = threadIdx.x, wid = tid >> 6, lane = tid & 63;
  const int wr = wid >> 2, wc = wid & 3;
  const int crow = (lane >> 4) << 2, ccol = lane & 15;
  #pragma unroll
  for (int f = 0; f < 8; ++f) {
    int base16 = (m0 + wr * 128) >> 4;
    #pragma unroll
    for (int n = 0; n < 4; ++n) {
      int col = n0 + wc * 64 + n * 16 + ccol;
      #pragma unroll
      for (int j = 0; j < 4; ++j) {
        int r = 32 * (base16 + f) + 16 + crow + j;   // interleaved W1 row (readout slot)
        W1[(size_t)r * DIM + col] = (__bf16)acc[f][n][j];
      }
    }
  }
}

// ======== merged main+kv GEMM launch: blocks [0,1024) = main body, [1024,1536) = kv body ======
// Both bodies are byte-identical to round-16's individually replay-proven kernels; the branch
// is block-uniform; outputs disjoint (out vs Yb); inputs read-only. No new sync structure.
__global__ void __launch_bounds__(512, 1)
gemm_mainkv_kernel(const __bf16* __restrict__ Xb, const __bf16* __restrict__ W1,
                   const __bf16* __restrict__ Wkv, const float* __restrict__ hidden,
                   float* __restrict__ out, __bf16* __restrict__ Yb) {
  __shared__ __attribute__((aligned(16))) char smem[131072];
  if (blockIdx.x < 1024) {
    // ---- main body: out = hidden + sigmoid(X@Wg^T) * (X@W2^T), W1 interleaved, N=4096 ----
    const int x = blockIdx.x & 7;        // XCD
    const int l = blockIdx.x >> 3;       // 0..127
    const int bm = x * 8 + (l & 7);      // 0..63
    const int bn = l >> 3;               // 0..15
    const int m0 = bm * 256, n0 = bn * 256;
    f32x4 acc[8][4] = {};
    gemm256_core(Xb, DIM, W1, DIM, m0, n0, 64, smem, acc);

    const int tid = threadIdx.x, wid = tid >> 6, lane = tid & 63;
    const int wr = wid >> 2, wc = wid & 3;
    const int crow = (lane >> 4) << 2, ccol = lane & 15;
    #pragma unroll
    for (int f = 0; f < 8; ++f) {
      int row = m0 + wr * 128 + f * 16 + crow;
      #pragma unroll
      for (int np = 0; np < 2; ++np) {
        int col = (n0 >> 1) + wc * 32 + np * 16 + ccol;
        #pragma unroll
        for (int j = 0; j < 4; ++j) {
          size_t idx = (size_t)(row + j) * DIM + col;
          float gv = 1.0f / (1.0f + __expf(-acc[f][2 * np][j]));
          out[idx] = hidden[idx] + gv * acc[f][2 * np + 1][j];
        }
      }
    }
  } else {
    // ---- kv body: Yb[:, 0..2047] = X @ [Wk;Wv]^T  (Yb stride NKVQ) ----
    const int bb = blockIdx.x - 1024;    // 0..511
    const int x = bb & 7;                // XCD
    const int l = bb >> 3;               // 0..63
    const int bm = x * 8 + (l & 7);      // 0..63
    const int bn = l >> 3;               // 0..7
    const int m0 = bm * 256, n0 = bn * 256;
    f32x4 acc[8][4] = {};
    gemm256_core(Xb, DIM, Wkv, DIM, m0, n0, 64, smem, acc);

    __syncthreads();
    const int tid = threadIdx.x, wid = tid >> 6, lane = tid & 63;
    const int wr = wid >> 2, wc = wid & 3;
    const int crow = (lane >> 4) << 2, ccol = lane & 15;
    #pragma unroll
    for (int f = 0; f < 8; ++f)
      #pragma unroll
      for (int n = 0; n < 4; ++n)
        #pragma unroll
        for (int j = 0; j < 4; ++j) {
          int r = wr * 128 + f * 16 + crow + j;
          int c = wc * 64 + n * 16 + ccol;
          *(__bf16*)(smem + r * 512 + ((c * 2) ^ ((r & 7) << 4))) = (__bf16)acc[f][n][j];
        }
    __syncthreads();
    const int rsub = tid >> 5, ch = tid & 31;
    #pragma unroll
    for (int p = 0; p < 16; ++p) {
      int r = p * 16 + rsub;
      bf16x8 v = *(const bf16x8*)(smem + r * 512 + ((ch * 16) ^ ((r & 7) << 4)));
      __builtin_nontemporal_store(__builtin_bit_cast(int4v, v),
          (int4v*)(Yb + (size_t)(m0 + r) * NKVQ + n0 + ch * 8));
    }
  }
}

// ---------------- memory update partials (round-9 EXACT, NKVQ stride) ----------------
__global__ void __launch_bounds__(256)
mem_update_kernel(const __bf16* __restrict__ Y, float* __restrict__ part) {
  const int h = blockIdx.x & 15, sp = blockIdx.x >> 4;
  __shared__ __attribute__((aligned(16))) __bf16 KT[64 * 32];
  __shared__ __attribute__((aligned(16))) __bf16 VT[64 * 32];
  const int tid = threadIdx.x, wid = tid >> 6, lane = tid & 63;
  const int lrow = lane & 15, lk = (lane >> 4) * 8;
  const __bf16* Kbase = Y + (size_t)sp * 1024 * NKVQ + h * 64;
  const __bf16* Vbase = Kbase + 1024;
  f32x4 acc[4] = {};
  const int t = tid >> 3, c8 = (tid & 7) * 8;
  for (int t0 = 0; t0 < 1024; t0 += 32) {
    __syncthreads();
    bf16x8 kv = *(const bf16x8*)(Kbase + (size_t)(t0 + t) * NKVQ + c8);
    bf16x8 vv = *(const bf16x8*)(Vbase + (size_t)(t0 + t) * NKVQ + c8);
    #pragma unroll
    for (int j = 0; j < 8; ++j) {
      KT[(c8 + j) * 32 + t] = kv[j];
      VT[(c8 + j) * 32 + t] = vv[j];
    }
    __syncthreads();
    bf16x8 af = *(const bf16x8*)(KT + (wid * 16 + lrow) * 32 + lk);
    #pragma unroll
    for (int n = 0; n < 4; ++n) {
      bf16x8 bf_ = *(const bf16x8*)(VT + (n * 16 + lrow) * 32 + lk);
      acc[n] = __builtin_amdgcn_mfma_f32_16x16x32_bf16(af, bf_, acc[n], 0, 0, 0);
    }
  }
  float* pp = part + ((size_t)sp * 16 + h) * 4096;
  const int crow = wid * 16 + (lane >> 4) * 4, ccol = lane & 15;
  #pragma unroll
  for (int n = 0; n < 4; ++n)
    #pragma unroll
    for (int r = 0; r < 4; ++r)
      pp[(crow + r) * 64 + n * 16 + ccol] = acc[n][r];
}

// ---------------- memory reduce: out = 0.99*mem + sum_sp part ----------------
__global__ void mem_reduce_kernel(const float* __restrict__ part, const float* __restrict__ mem,
                                  float* __restrict__ out) {
  int i = blockIdx.x * blockDim.x + threadIdx.x;
  float s = 0.99f * mem[i];
  #pragma unroll
  for (int sp = 0; sp < 16; ++sp) s += part[sp * 65536 + i];
  out[i] = s;
}

extern "C" void kernel_launch(void* const* d_in, const int* in_sizes, int n_in,
                              void* d_out, int out_size, void* d_ws, size_t ws_size,
                              hipStream_t stream) {
  const float* hidden = (const float*)d_in[0];
  const float* memory = (const float*)d_in[1];
  const float* Wk = (const float*)d_in[2];
  const float* Wv = (const float*)d_in[3];
  const float* Wq = (const float*)d_in[4];
  const float* Wg = (const float*)d_in[5];
  const float* Wo = (const float*)d_in[6];
  float* out = (float*)d_out;
  float* mem_out = out + (size_t)TOKENS * DIM;

  char* ws = (char*)d_ws;
  __bf16* Xb   = (__bf16*)(ws);                    // 16384x2048  ( 67,108,864 B)
  __bf16* W1   = (__bf16*)(ws + 67108864);         // 4096x2048   ( 16,777,216 B) interleaved
  __bf16* Wkv  = (__bf16*)(ws + 83886080);         // 2048x2048   (  8,388,608 B)
  __bf16* Weff = (__bf16*)(ws + 92274688);         // 2048x1024   (  4,194,304 B)
  __bf16* WqT  = (__bf16*)(ws + 96468992);         // 2048x1024   (  4,194,304 B)
  __bf16* Yb   = (__bf16*)(ws + 100663296);        // 16384x3072  (100,663,296 B)
  float*  part = (float*)(ws + 201326592);         // 16x16x64x64 (  4,194,304 B)
  // total 205,520,896 B

  // ONE prep launch: Xb, W1 gate rows, Wkv, Weff, WqT
  prep_all_kernel<<<29184, 256, 0, stream>>>(hidden, Wg, Wk, Wv, Wo, memory, Wq,
                                             Xb, W1, Wkv, Weff, WqT);

  // W2 = Weff @ Wq -> interleaved readout rows of W1
  w2_kernel<<<64, 512, 0, stream>>>(Weff, WqT, W1);

  // merged main+kv GEMM (1536 blocks; bodies identical to round-16's separate kernels)
  gemm_mainkv_kernel<<<1536, 512, 0, stream>>>(Xb, W1, Wkv, hidden, out, Yb);

  // memory update
  mem_update_kernel<<<256, 256, 0, stream>>>(Yb, part);
  mem_reduce_kernel<<<256, 256, 0, stream>>>(part, memory, mem_out);
}

// Round 18
// 550.684 us; speedup vs baseline: 1.1169x; 1.0430x over previous
//
#include <hip/hip_runtime.h>
#include <hip/hip_bf16.h>

typedef __attribute__((ext_vector_type(4))) float f32x4;
typedef __bf16 bf16x8 __attribute__((ext_vector_type(8)));
typedef __bf16 bf16x4 __attribute__((ext_vector_type(4)));
typedef int int4v __attribute__((ext_vector_type(4)));

#define TOKENS 16384
#define DIM    2048
#define NKVQ   3072   // Yb row stride (cols 0..1023 = K, 1024..2047 = V)

__device__ __forceinline__ void gload_lds16(const void* g, void* l) {
  __builtin_amdgcn_global_load_lds((const __attribute__((address_space(1))) void*)g,
                                   (__attribute__((address_space(3))) void*)l, 16, 0, 0);
}

__device__ __forceinline__ bf16x8 cvt8(float4 a, float4 b) {
  bf16x8 o;
  o[0] = (__bf16)a.x; o[1] = (__bf16)a.y; o[2] = (__bf16)a.z; o[3] = (__bf16)a.w;
  o[4] = (__bf16)b.x; o[5] = (__bf16)b.y; o[6] = (__bf16)b.z; o[7] = (__bf16)b.w;
  return o;
}

// ============ fused prep: ONE launch for all casts/transposes/precomputes =====================
// (round-16/17 exact; passed)
__global__ void __launch_bounds__(256)
prep_all_kernel(const float* __restrict__ hidden, const float* __restrict__ Wg,
                const float* __restrict__ Wk, const float* __restrict__ Wv,
                const float* __restrict__ Wo, const float* __restrict__ mem,
                const float* __restrict__ Wq,
                __bf16* __restrict__ Xb, __bf16* __restrict__ W1,
                __bf16* __restrict__ Wkv, __bf16* __restrict__ Weff,
                __bf16* __restrict__ WqT) {
  __shared__ __bf16 Ts[64][68];
  const int b = blockIdx.x, t = threadIdx.x;
  if (b < 16384) {
    int i = b * 256 + t;
    const float4* s = (const float4*)hidden;
    ((bf16x8*)Xb)[i] = cvt8(s[2 * i], s[2 * i + 1]);
  } else if (b < 20480) {
    int i = (b - 16384) * 256 + t;
    if (i < 524288) {
      int g = i >> 8, c8 = (i & 255) * 8;
      const float4* s = (const float4*)(Wg + (size_t)g * DIM + c8);
      int r = 32 * (g >> 4) + (g & 15);   // interleaved gate slot
      *(bf16x8*)(W1 + (size_t)r * DIM + c8) = cvt8(s[0], s[1]);
    } else if (i < 786432) {
      int j = i - 524288;
      const float4* s = (const float4*)Wk + 2 * j;
      ((bf16x8*)Wkv)[j] = cvt8(s[0], s[1]);
    } else {
      int k = i - 786432;
      const float4* s = (const float4*)Wv + 2 * k;
      ((bf16x8*)(Wkv + 2097152))[k] = cvt8(s[0], s[1]);
    }
  } else if (b < 28672) {
    int idx = (b - 20480) * 256 + t;      // 0..2097151
    int d = idx >> 10, hk = idx & 1023, h = hk >> 6;
    const float* wo = Wo + d * 1024 + h * 64;
    const float* mm = mem + hk * 64;
    float s = 0.f;
    #pragma unroll 8
    for (int v = 0; v < 64; ++v) s += wo[v] * mm[v];
    Weff[idx] = (__bf16)s;
  } else {
    int bb = b - 28672;                   // 0..511
    const int ti = bb >> 5, di = bb & 31; // 16 x 32 tiles
    const int h0 = ti << 6, d0 = di << 6;
    const int r0 = t >> 4, c4 = t & 15;
    #pragma unroll
    for (int i = 0; i < 4; ++i) {
      int row = r0 + i * 16;
      float4 v = *(const float4*)(Wq + (size_t)(h0 + row) * DIM + d0 + c4 * 4);
      Ts[row][c4 * 4 + 0] = (__bf16)v.x; Ts[row][c4 * 4 + 1] = (__bf16)v.y;
      Ts[row][c4 * 4 + 2] = (__bf16)v.z; Ts[row][c4 * 4 + 3] = (__bf16)v.w;
    }
    __syncthreads();
    const int d = t >> 2, sq = t & 3;
    #pragma unroll
    for (int g = 0; g < 2; ++g) {
      bf16x8 o;
      #pragma unroll
      for (int k = 0; k < 8; ++k) o[k] = Ts[sq * 16 + g * 8 + k][d];
      *(bf16x8*)(WqT + (size_t)(d0 + d) * 1024 + h0 + sq * 16 + g * 8) = o;
    }
  }
}

// ================= 256x256 MFMA core, BK=32, 4-buf ring (C = A @ B^T) ========================
// EXACT round-6/14/16/17 version (7/7 replay-validated passes).
__device__ __forceinline__ void gemm256_core(
    const __bf16* __restrict__ A, int lda,
    const __bf16* __restrict__ B, int ldb,
    int m0, int n0, int nt, char* sm, f32x4 acc[8][4]) {

  const int tid = threadIdx.x, lane = tid & 63, wid = tid >> 6;
  const int wr = wid >> 2, wc = wid & 3;
  const int lrow = lane & 15, kc = lane >> 4;

  int offA[8], offB[4];
  #pragma unroll
  for (int m = 0; m < 8; ++m) {
    int u = (wr * 128 + m * 16 + lrow) * 4 + kc;
    offA[m] = (u ^ ((u >> 3) & 7)) << 4;
  }
  #pragma unroll
  for (int n = 0; n < 4; ++n) {
    int u = (wc * 64 + n * 16 + lrow) * 4 + kc;
    offB[n] = ((u ^ ((u >> 3) & 7)) << 4) + 16384;
  }

  const __bf16* pSA[2]; const __bf16* pSB[2];
  #pragma unroll
  for (int s = 0; s < 2; ++s) {
    int U = s * 512 + tid;
    int u = U ^ ((U >> 3) & 7);
    pSA[s] = A + (size_t)(m0 + (u >> 2)) * lda + (u & 3) * 8;
    pSB[s] = B + (size_t)(n0 + (u >> 2)) * ldb + (u & 3) * 8;
  }

  bf16x8 bvS0[4], bvS1[4];

#define BARX() asm volatile("s_barrier" ::: "memory")
#define VM4()  asm volatile("s_waitcnt vmcnt(4)" ::: "memory")
#define VM0()  asm volatile("s_waitcnt vmcnt(0)" ::: "memory")
#define NOVM
#define NOSTAGE
#define STAGE(bb, tt) do { \
    char* sA = sm + (bb) * 32768 + tid * 16; \
    gload_lds16(pSA[0] + (tt) * 32, sA); \
    gload_lds16(pSA[1] + (tt) * 32, sA + 8192); \
    gload_lds16(pSB[0] + (tt) * 32, sA + 16384); \
    gload_lds16(pSB[1] + (tt) * 32, sA + 24576); } while (0)

#define PH(bufC, bufN, C, N, STG, WT) do { \
    const char* bC = sm + (bufC) * 32768; \
    const char* bN = sm + (bufN) * 32768; \
    bf16x8 av[8]; \
    _Pragma("unroll") for (int m = 0; m < 8; ++m) av[m] = *(const bf16x8*)(bC + offA[m]); \
    _Pragma("unroll") for (int n = 0; n < 4; ++n) bvS##N[n] = *(const bf16x8*)(bN + offB[n]); \
    STG; \
    __builtin_amdgcn_s_setprio(1); \
    _Pragma("unroll") for (int m = 0; m < 8; ++m) \
      _Pragma("unroll") for (int n = 0; n < 4; ++n) \
        acc[m][n] = __builtin_amdgcn_mfma_f32_16x16x32_bf16(av[m], bvS##C[n], acc[m][n], 0, 0, 0); \
    __builtin_amdgcn_s_setprio(0); \
    WT; BARX(); } while (0)

#define PHF(bufC, C) do { \
    const char* bC = sm + (bufC) * 32768; \
    bf16x8 av[8]; \
    _Pragma("unroll") for (int m = 0; m < 8; ++m) av[m] = *(const bf16x8*)(bC + offA[m]); \
    __builtin_amdgcn_s_setprio(1); \
    _Pragma("unroll") for (int m = 0; m < 8; ++m) \
      _Pragma("unroll") for (int n = 0; n < 4; ++n) \
        acc[m][n] = __builtin_amdgcn_mfma_f32_16x16x32_bf16(av[m], bvS##C[n], acc[m][n], 0, 0, 0); \
    __builtin_amdgcn_s_setprio(0); } while (0)

  STAGE(0, 0); STAGE(1, 1); STAGE(2, 2);
  VM4(); BARX();
  #pragma unroll
  for (int n = 0; n < 4; ++n) bvS0[n] = *(const bf16x8*)(sm + offB[n]);

  for (int i = 0, e = (nt - 4) >> 2; i < e; ++i) {
    const int t = i << 2;
    PH(0, 1, 0, 1, STAGE(3, t + 3), VM4());
    PH(1, 2, 1, 0, STAGE(0, t + 4), VM4());
    PH(2, 3, 0, 1, STAGE(1, t + 5), VM4());
    PH(3, 0, 1, 0, STAGE(2, t + 6), VM4());
  }
  PH(0, 1, 0, 1, STAGE(3, nt - 1), VM4());
  PH(1, 2, 1, 0, NOSTAGE, VM0());
  PH(2, 3, 0, 1, NOSTAGE, NOVM);
  PHF(3, 1);
#undef PH
#undef PHF
#undef STAGE
#undef BARX
#undef VM4
#undef VM0
#undef NOVM
#undef NOSTAGE
}

// ---------------- W2 GEMM (round-14/16/17 exact): W2 = Weff @ WqT^T -> W1 interleaved rows ----
__global__ void __launch_bounds__(512, 1)
w2_kernel(const __bf16* __restrict__ Weff, const __bf16* __restrict__ WqT,
          __bf16* __restrict__ W1) {
  __shared__ __attribute__((aligned(16))) char smem[131072];
  const int bm = blockIdx.x >> 3, bn = blockIdx.x & 7;
  const int m0 = bm * 256, n0 = bn * 256;
  f32x4 acc[8][4] = {};
  gemm256_core(Weff, 1024, WqT, 1024, m0, n0, 32, smem, acc);

  const int tid = threadIdx.x, wid = tid >> 6, lane = tid & 63;
  const int wr = wid >> 2, wc = wid & 3;
  const int crow = (lane >> 4) << 2, ccol = lane & 15;
  #pragma unroll
  for (int f = 0; f < 8; ++f) {
    int base16 = (m0 + wr * 128) >> 4;
    #pragma unroll
    for (int n = 0; n < 4; ++n) {
      int col = n0 + wc * 64 + n * 16 + ccol;
      #pragma unroll
      for (int j = 0; j < 4; ++j) {
        int r = 32 * (base16 + f) + 16 + crow + j;   // interleaved W1 row (readout slot)
        W1[(size_t)r * DIM + col] = (__bf16)acc[f][n][j];
      }
    }
  }
}

// ======== merged main+kv GEMM launch (round-17 exact; passed) ================================
__global__ void __launch_bounds__(512, 1)
gemm_mainkv_kernel(const __bf16* __restrict__ Xb, const __bf16* __restrict__ W1,
                   const __bf16* __restrict__ Wkv, const float* __restrict__ hidden,
                   float* __restrict__ out, __bf16* __restrict__ Yb) {
  __shared__ __attribute__((aligned(16))) char smem[131072];
  if (blockIdx.x < 1024) {
    const int x = blockIdx.x & 7;        // XCD
    const int l = blockIdx.x >> 3;       // 0..127
    const int bm = x * 8 + (l & 7);      // 0..63
    const int bn = l >> 3;               // 0..15
    const int m0 = bm * 256, n0 = bn * 256;
    f32x4 acc[8][4] = {};
    gemm256_core(Xb, DIM, W1, DIM, m0, n0, 64, smem, acc);

    const int tid = threadIdx.x, wid = tid >> 6, lane = tid & 63;
    const int wr = wid >> 2, wc = wid & 3;
    const int crow = (lane >> 4) << 2, ccol = lane & 15;
    #pragma unroll
    for (int f = 0; f < 8; ++f) {
      int row = m0 + wr * 128 + f * 16 + crow;
      #pragma unroll
      for (int np = 0; np < 2; ++np) {
        int col = (n0 >> 1) + wc * 32 + np * 16 + ccol;
        #pragma unroll
        for (int j = 0; j < 4; ++j) {
          size_t idx = (size_t)(row + j) * DIM + col;
          float gv = 1.0f / (1.0f + __expf(-acc[f][2 * np][j]));
          out[idx] = hidden[idx] + gv * acc[f][2 * np + 1][j];
        }
      }
    }
  } else {
    const int bb = blockIdx.x - 1024;    // 0..511
    const int x = bb & 7;                // XCD
    const int l = bb >> 3;               // 0..63
    const int bm = x * 8 + (l & 7);      // 0..63
    const int bn = l >> 3;               // 0..7
    const int m0 = bm * 256, n0 = bn * 256;
    f32x4 acc[8][4] = {};
    gemm256_core(Xb, DIM, Wkv, DIM, m0, n0, 64, smem, acc);

    __syncthreads();
    const int tid = threadIdx.x, wid = tid >> 6, lane = tid & 63;
    const int wr = wid >> 2, wc = wid & 3;
    const int crow = (lane >> 4) << 2, ccol = lane & 15;
    #pragma unroll
    for (int f = 0; f < 8; ++f)
      #pragma unroll
      for (int n = 0; n < 4; ++n)
        #pragma unroll
        for (int j = 0; j < 4; ++j) {
          int r = wr * 128 + f * 16 + crow + j;
          int c = wc * 64 + n * 16 + ccol;
          *(__bf16*)(smem + r * 512 + ((c * 2) ^ ((r & 7) << 4))) = (__bf16)acc[f][n][j];
        }
    __syncthreads();
    const int rsub = tid >> 5, ch = tid & 31;
    #pragma unroll
    for (int p = 0; p < 16; ++p) {
      int r = p * 16 + rsub;
      bf16x8 v = *(const bf16x8*)(smem + r * 512 + ((ch * 16) ^ ((r & 7) << 4)));
      __builtin_nontemporal_store(__builtin_bit_cast(int4v, v),
          (int4v*)(Yb + (size_t)(m0 + r) * NKVQ + n0 + ch * 8));
    }
  }
}

// ---------------- memory update partials: 32 splits x 16 heads, double-buffered LDS ----------
// part[sp][h] = K_h^T V_h over 512 tokens. 1 barrier/iter; global prefetch overlaps MFMA.
__global__ void __launch_bounds__(256)
mem_update_kernel(const __bf16* __restrict__ Y, float* __restrict__ part) {
  const int h = blockIdx.x & 15, sp = blockIdx.x >> 4;   // sp 0..31
  __shared__ __attribute__((aligned(16))) __bf16 KT[2][64 * 32];
  __shared__ __attribute__((aligned(16))) __bf16 VT[2][64 * 32];
  const int tid = threadIdx.x, wid = tid >> 6, lane = tid & 63;
  const int lrow = lane & 15, lk = (lane >> 4) * 8;
  const __bf16* Kbase = Y + (size_t)sp * 512 * NKVQ + h * 64;
  const __bf16* Vbase = Kbase + 1024;
  f32x4 acc[4] = {};
  const int t = tid >> 3, c8 = (tid & 7) * 8;

  bf16x8 kv = *(const bf16x8*)(Kbase + (size_t)t * NKVQ + c8);
  bf16x8 vv = *(const bf16x8*)(Vbase + (size_t)t * NKVQ + c8);
  int p = 0;
  for (int t0 = 0; t0 < 512; t0 += 32) {
    #pragma unroll
    for (int j = 0; j < 8; ++j) {
      KT[p][(c8 + j) * 32 + t] = kv[j];
      VT[p][(c8 + j) * 32 + t] = vv[j];
    }
    if (t0 + 32 < 512) {
      kv = *(const bf16x8*)(Kbase + (size_t)(t0 + 32 + t) * NKVQ + c8);
      vv = *(const bf16x8*)(Vbase + (size_t)(t0 + 32 + t) * NKVQ + c8);
    }
    __syncthreads();
    bf16x8 af = *(const bf16x8*)(&KT[p][(wid * 16 + lrow) * 32 + lk]);
    #pragma unroll
    for (int n = 0; n < 4; ++n) {
      bf16x8 bf_ = *(const bf16x8*)(&VT[p][(n * 16 + lrow) * 32 + lk]);
      acc[n] = __builtin_amdgcn_mfma_f32_16x16x32_bf16(af, bf_, acc[n], 0, 0, 0);
    }
    p ^= 1;
  }
  float* pp = part + ((size_t)sp * 16 + h) * 4096;
  const int crow = wid * 16 + (lane >> 4) * 4, ccol = lane & 15;
  #pragma unroll
  for (int n = 0; n < 4; ++n)
    #pragma unroll
    for (int r = 0; r < 4; ++r)
      pp[(crow + r) * 64 + n * 16 + ccol] = acc[n][r];
}

// ---------------- memory reduce: out = 0.99*mem + sum_sp part (float4, 32 partials) ----------
__global__ void mem_reduce_kernel(const float* __restrict__ part, const float* __restrict__ mem,
                                  float* __restrict__ out) {
  int i4 = blockIdx.x * blockDim.x + threadIdx.x;   // 16384
  float4 m = ((const float4*)mem)[i4];
  float4 s = {0.99f * m.x, 0.99f * m.y, 0.99f * m.z, 0.99f * m.w};
  #pragma unroll
  for (int sp = 0; sp < 32; ++sp) {
    float4 p = ((const float4*)(part + (size_t)sp * 65536))[i4];
    s.x += p.x; s.y += p.y; s.z += p.z; s.w += p.w;
  }
  ((float4*)out)[i4] = s;
}

extern "C" void kernel_launch(void* const* d_in, const int* in_sizes, int n_in,
                              void* d_out, int out_size, void* d_ws, size_t ws_size,
                              hipStream_t stream) {
  const float* hidden = (const float*)d_in[0];
  const float* memory = (const float*)d_in[1];
  const float* Wk = (const float*)d_in[2];
  const float* Wv = (const float*)d_in[3];
  const float* Wq = (const float*)d_in[4];
  const float* Wg = (const float*)d_in[5];
  const float* Wo = (const float*)d_in[6];
  float* out = (float*)d_out;
  float* mem_out = out + (size_t)TOKENS * DIM;

  char* ws = (char*)d_ws;
  __bf16* Xb   = (__bf16*)(ws);                    // 16384x2048  ( 67,108,864 B)
  __bf16* W1   = (__bf16*)(ws + 67108864);         // 4096x2048   ( 16,777,216 B) interleaved
  __bf16* Wkv  = (__bf16*)(ws + 83886080);         // 2048x2048   (  8,388,608 B)
  __bf16* Weff = (__bf16*)(ws + 92274688);         // 2048x1024   (  4,194,304 B)
  __bf16* WqT  = (__bf16*)(ws + 96468992);         // 2048x1024   (  4,194,304 B)
  __bf16* Yb   = (__bf16*)(ws + 100663296);        // 16384x3072  (100,663,296 B)
  float*  part = (float*)(ws + 201326592);         // 32x16x64x64 (  8,388,608 B)
  // total 209,715,200 B (< proven-available 264 MB)

  // ONE prep launch: Xb, W1 gate rows, Wkv, Weff, WqT
  prep_all_kernel<<<29184, 256, 0, stream>>>(hidden, Wg, Wk, Wv, Wo, memory, Wq,
                                             Xb, W1, Wkv, Weff, WqT);

  // W2 = Weff @ Wq -> interleaved readout rows of W1
  w2_kernel<<<64, 512, 0, stream>>>(Weff, WqT, W1);

  // merged main+kv GEMM
  gemm_mainkv_kernel<<<1536, 512, 0, stream>>>(Xb, W1, Wkv, hidden, out, Yb);

  // memory update (32 splits, double-buffered) + reduce
  mem_update_kernel<<<512, 256, 0, stream>>>(Yb, part);
  mem_reduce_kernel<<<64, 256, 0, stream>>>(part, memory, mem_out);
}